// Round 12
// baseline (247.762 us; speedup 1.0000x reference)
//
#include <hip/hip_runtime.h>
#include <hip/hip_bf16.h>

#define B_SZ 16384
#define N_SZ 64
#define D_SZ 64
#define H_SZ 128
#define R_PB 2              // rows per block (one per wave; phases 1-4 are wave-private)
#define ARS 68              // A row stride, bf16 elems (136 B; 2-way banks = free)
#define CRS 264             // comb row stride, bf16 elems (payload 256; 528 B keeps 16B align)

#define INV_2PI 0.15915494309189535f
#define TWO_PI  6.283185307179586f

typedef short bf16x8 __attribute__((ext_vector_type(8)));
typedef float f32x4  __attribute__((ext_vector_type(4)));
typedef float f32x2  __attribute__((ext_vector_type(2)));

__device__ __forceinline__ float bits2f(unsigned short r){union{unsigned i;float f;}c;c.i=((unsigned)r)<<16;return c.f;}
__device__ __forceinline__ unsigned f2bfbits(float f){
    __hip_bfloat16 h = __float2bfloat16(f);           // RNE
    unsigned short u;
    __builtin_memcpy(&u, &h, 2);
    return (unsigned)u;
}
__device__ __forceinline__ unsigned pack2bf(float a, float b){   // v_cvt_pk_bf16_f32
    __hip_bfloat162 h = __float22bfloat162_rn(make_float2(a, b));
    unsigned r;
    __builtin_memcpy(&r, &h, 4);
    return r;
}
__device__ __forceinline__ float bf2f(__hip_bfloat16 x) { return __bfloat162float(x); }

template<int CTRL>
__device__ __forceinline__ float dpp_add(float v){
    int t = __builtin_amdgcn_mov_dpp(__builtin_bit_cast(int, v), CTRL, 0xf, 0xf, true);
    return v + __builtin_bit_cast(float, t);
}

// cos of a value ALREADY in revolutions: v_fract (ISA range reduction) + v_cos.
__device__ __forceinline__ float cos_rev(float v_rev){
    return __builtin_amdgcn_cosf(__builtin_amdgcn_fractf(v_rev));
}

// 1/max(sqrt(ss),1e-12) as a single v_rsq + clamp (ss >= 0 by construction;
// rsq(0)=inf -> clamped to 1e12). Replaces IEEE sqrt + full divide.
__device__ __forceinline__ float inv_norm(float ss){
    return fminf(__builtin_amdgcn_rsqf(ss), 1e12f);
}

// Clamped Pade 3/2: tanh(x) ~ x(27+x^2)/(27+9x^2), clamp [-1,1].
__device__ __forceinline__ float tanh_fast(float x){
    const float t   = x * x;
    const float num = x * (27.0f + t);
    const float den = fmaf(t, 9.0f, 27.0f);
    const float r   = __fdividef(num, den);            // v_rcp + v_mul
    return fminf(1.0f, fmaxf(-1.0f, r));               // v_med3
}

// FMODE 0: bf16 tensors, 1: f32 tensors
template<int FMODE>
__device__ __forceinline__ float LD(const void* p, int i) {
    if constexpr (FMODE == 0) return bf2f(((const __hip_bfloat16*)p)[i]);
    else                      return ((const float*)p)[i];
}

// mask modes: 0 = int32, 1 = int8/bool, 2 = bf16, 3 = f32
__device__ __forceinline__ float mval(const void* p, int i, int mode) {
    if (mode == 0) return ((const int*)p)[i]            ? 1.0f : 0.0f;
    if (mode == 1) return ((const unsigned char*)p)[i]  ? 1.0f : 0.0f;
    if (mode == 2) return ((const unsigned short*)p)[i] ? 1.0f : 0.0f;
    return ((const unsigned int*)p)[i]                  ? 1.0f : 0.0f;
}

// dt_node strictly positive: bf16 words never set bit15; f32 low-mantissa words do
__device__ __forceinline__ int detect_f32(const void* p) {
    const uint4* q = (const uint4*)p;
    unsigned o = 0;
    #pragma unroll
    for (int i = 0; i < 8; ++i) { uint4 v = q[i]; o |= v.x | v.y | v.z | v.w; }
    return (o & 0x80008000u) ? 1 : 0;
}

// 0/1-valued mask, 128 head bytes
__device__ __forceinline__ int detect_mask_mode(const void* p) {
    const uint4* q = (const uint4*)p;
    unsigned oa = 0, ofe = 0;
    #pragma unroll
    for (int i = 0; i < 8; ++i) {
        uint4 v = q[i];
        unsigned w = v.x | v.y | v.z | v.w;
        oa  |= w;
        ofe |= (v.x & 0xFEFEFEFEu) | (v.y & 0xFEFEFEFEu) | (v.z & 0xFEFEFEFEu) | (v.w & 0xFEFEFEFEu);
    }
    if ((oa & 0xFFFFFF00u) == 0) return 0;   // int32 0/1
    if (ofe == 0)                return 1;   // bool/int8
    if (oa & 0x000000FEu)        return 2;   // bf16
    return 3;                                // f32
}

// ---------------- prep: W1/W2 -> MFMA B-fragment layout in d_ws (16 KB), grid=4 ----------------
__global__ void prep_kernel(const void* dt_node, const void* att_W1, const void* att_W2,
                            void* ws) {
    const int t     = blockIdx.x * 256 + threadIdx.x;
    const int fmode = detect_f32(dt_node);
    const int fi  = t >> 6, ln = t & 63;
    const int et  = fi >> 2, ks = fi & 3;
    const int m16 = ln & 15, qd = ln >> 4;
    const int col = et * 16 + m16;
    unsigned short s[8];
    #pragma unroll
    for (int j = 0; j < 8; ++j) {
        const int i = ks * 32 + qd * 8 + j;
        if (fmode == 0) {
            s[j] = (i < 64) ? ((const unsigned short*)att_W1)[i * D_SZ + col]
                            : ((const unsigned short*)att_W2)[(i - 64) * D_SZ + col];
        } else {
            const float v = (i < 64) ? ((const float*)att_W1)[i * D_SZ + col]
                                     : ((const float*)att_W2)[(i - 64) * D_SZ + col];
            s[j] = (unsigned short)f2bfbits(v);
        }
    }
    ((uint4*)ws)[t] = make_uint4(((unsigned)s[0]) | (((unsigned)s[1]) << 16),
                                 ((unsigned)s[2]) | (((unsigned)s[3]) << 16),
                                 ((unsigned)s[4]) | (((unsigned)s[5]) << 16),
                                 ((unsigned)s[6]) | (((unsigned)s[7]) << 16));
}

struct Smem {
    alignas(16) unsigned short A[R_PB * 64 * ARS];  // [row][n 0..63][d] neighbors only (node lives in comb)
    alignas(16) unsigned short comb[R_PB * CRS];    // [node_f(64) | agg(64) | hist(128)] bf16 + pad
    alignas(16) float prm[4][D_SZ];                 // t2v_w/2pi | t2v_b/2pi | node_w | 2*node_b
    float att[R_PB][N_SZ];                          // phase2: att scores; phase3 overwrites wn
};
// LDS total (R_PB=2) = 17408 + 1056 + 1024 + 512 = 20000 B -> 7-8 blocks/CU if pool permits.

// ---- 4-row interleaved feature chunk (rows of ONE wave's batch-row) ----
__device__ __forceinline__ void feat_row4(const float t[4], const float dc[4],
                                          const float* sw, const float* sb,
                                          const float* snw, const float* snb,
                                          int c, unsigned short* dstA, int rstride) {
    f32x2 fp[4][8];
    float ss[4] = {0.f, 0.f, 0.f, 0.f};
    #pragma unroll
    for (int g = 0; g < 8; ++g) {
        const f32x2 w  = *(const f32x2*)(sw  + 2 * g);
        const f32x2 b  = *(const f32x2*)(sb  + 2 * g);
        const f32x2 nw = *(const f32x2*)(snw + 2 * g);
        const f32x2 nb = *(const f32x2*)(snb + 2 * g);
        #pragma unroll
        for (int r = 0; r < 4; ++r) {
            f32x2 v = w * t[r] + b;                     // v_pk_fma_f32 (REVOLUTIONS)
            f32x2 cv;
            cv.x = (c == 0 && g == 0) ? v.x * TWO_PI : cos_rev(v.x);
            cv.y = cos_rev(v.y);
            f32x2 f = cv + (nw * dc[r] + nb);
            ss[r] = fmaf(f.x, f.x, ss[r]);
            ss[r] = fmaf(f.y, f.y, ss[r]);
            fp[r][g] = f;
        }
    }
    #pragma unroll
    for (int r = 0; r < 4; ++r) {
        float s = ss[r];
        s = dpp_add<0xB1>(s);                           // quad_perm xor1
        s = dpp_add<0x4E>(s);                           // quad_perm xor2
        const float inv = inv_norm(s);
        unsigned pk[8];
        #pragma unroll
        for (int g = 0; g < 8; ++g)
            pk[g] = pack2bf(fp[r][g].x * inv, fp[r][g].y * inv);
        uint4* d = (uint4*)(dstA + r * rstride);
        d[0] = make_uint4(pk[0], pk[1], pk[2], pk[3]);
        d[1] = make_uint4(pk[4], pk[5], pk[6], pk[7]);
    }
}

// single-row variant (node tail, lanes 0-3)
__device__ __forceinline__ void feat_row(float t, float dc,
                                         const float* sw, const float* sb,
                                         const float* snw, const float* snb,
                                         int c, unsigned short* dstC) {
    f32x2 fp[8]; float ss = 0.0f;
    #pragma unroll
    for (int g = 0; g < 8; ++g) {
        const f32x2 w  = *(const f32x2*)(sw  + 2 * g);
        const f32x2 b  = *(const f32x2*)(sb  + 2 * g);
        const f32x2 nw = *(const f32x2*)(snw + 2 * g);
        const f32x2 nb = *(const f32x2*)(snb + 2 * g);
        f32x2 v = w * t + b;
        f32x2 cv;
        cv.x = (c == 0 && g == 0) ? v.x * TWO_PI : cos_rev(v.x);
        cv.y = cos_rev(v.y);
        f32x2 f = cv + (nw * dc + nb);
        ss = fmaf(f.x, f.x, ss);
        ss = fmaf(f.y, f.y, ss);
        fp[g] = f;
    }
    ss = dpp_add<0xB1>(ss);
    ss = dpp_add<0x4E>(ss);
    const float inv = inv_norm(ss);
    unsigned pk[8];
    #pragma unroll
    for (int g = 0; g < 8; ++g)
        pk[g] = pack2bf(fp[g].x * inv, fp[g].y * inv);
    ((uint4*)dstC)[0] = make_uint4(pk[0], pk[1], pk[2], pk[3]);
    ((uint4*)dstC)[1] = make_uint4(pk[4], pk[5], pk[6], pk[7]);
}

template<int FMODE, bool USE_WS>
__device__ __forceinline__ void body(
    Smem& sm,
    const void* dt_node, const void* deg_node, const void* cc_node,
    const void* dt_neigh, const void* deg_neigh, const void* cc_neigh,
    const void* neigh_mask, const void* feature_hist,
    const void* t2v_w, const void* t2v_b, const void* node_w, const void* node_b,
    const void* att_W1, const void* att_W2, const void* att_v,
    const void* weight, void* out, const void* ws, int mmode, int b0, int tid)
{
    const int lane = tid & 63;
    const int wv   = tid >> 6;       // 0..1
    const int m16  = lane & 15;
    const int quad = lane >> 4;
    const int row  = b0 + wv;        // this wave's row; phases 1-4 are wave-private

    // ---- Prefetch (a): wave-private phase-1 inputs (16 feat-rows/pass, 4 passes) ----
    const int fb = lane >> 2;        // feat-row within pass; c = lane&3 = chunk
    float p1_dt[4], p1_deg[4], p1_cc[4];
    #pragma unroll
    for (int it = 0; it < 4; ++it) {
        const int idx = row * N_SZ + fb + it * 16;
        p1_dt[it]  = LD<FMODE>(dt_neigh,  idx);
        p1_deg[it] = LD<FMODE>(deg_neigh, idx);
        p1_cc[it]  = LD<FMODE>(cc_neigh,  idx);
    }
    const float pn_dt  = LD<FMODE>(dt_node,  row);
    const float pn_deg = LD<FMODE>(deg_node, row);
    const float pn_cc  = LD<FMODE>(cc_node,  row);

    // ---- Prefetch (b): phase-3 inputs for this row ----
    const int p3idx = row * N_SZ + lane;
    const float p3_dt = LD<FMODE>(dt_neigh, p3idx);
    const float p3_m  = mval(neigh_mask, p3idx, mmode);
    unsigned p3_hw = 0; float p3_h0 = 0.f, p3_h1 = 0.f;
    if constexpr (FMODE == 0) {
        p3_hw = ((const unsigned*)feature_hist)[row * 64 + lane];
    } else {
        const float* fh = (const float*)feature_hist + row * 2 * D_SZ + 2 * lane;
        p3_h0 = fh[0]; p3_h1 = fh[1];
    }
    float vep[4];
    #pragma unroll
    for (int et = 0; et < 4; ++et) vep[et] = LD<FMODE>(att_v, et * 16 + m16);

    // ---- Phase 0': EACH wave stages the FULL param block (benign identical-bits
    // race; a wave's own writes cover every entry it reads -> NO barrier).
    #pragma unroll
    for (int arr = 0; arr < 4; ++arr) {
        float v;
        if      (arr == 0) v = INV_2PI * LD<FMODE>(t2v_w,  lane);
        else if (arr == 1) v = INV_2PI * LD<FMODE>(t2v_b,  lane);
        else if (arr == 2) v = LD<FMODE>(node_w, lane);
        else               v = 2.0f * LD<FMODE>(node_b, lane);   // deg+cc biases folded
        sm.prm[arr][lane] = v;
    }

    // ---- Phase 1': wave-private features, 4 rows batched. No barrier after:
    // phases 2-4 read only this wave's LDS slices (same-wave RAW ordered by lgkmcnt).
    {
        const int c = lane & 3, d0 = c * 16;
        const float* sw  = sm.prm[0] + d0;
        const float* sb  = sm.prm[1] + d0;
        const float* snw = sm.prm[2] + d0;
        const float* snb = sm.prm[3] + d0;

        float tt[4], dcc[4];
        #pragma unroll
        for (int it = 0; it < 4; ++it) {
            tt[it]  = fabsf(p1_dt[it]);
            dcc[it] = p1_deg[it] + p1_cc[it];
        }
        feat_row4(tt, dcc, sw, sb, snw, snb, c,
                  sm.A + (wv * 64 + fb) * ARS + d0, 16 * ARS);

        if (fb == 0)   // lanes 0-3: node feature row -> comb only
            feat_row(fabsf(pn_dt), pn_deg + pn_cc, sw, sb, snw, snb, c,
                     sm.comb + wv * CRS + d0);
    }

    // ---- Phase 2: S + att for row r = wv ----
    {
        const int r = wv;
        const unsigned short* An = sm.comb + r * CRS + quad * 8;
        const bf16x8 a0 = *(const bf16x8*)An;          // node k  0..31
        const bf16x8 a1 = *(const bf16x8*)(An + 32);   // node k 32..63
        const bf16x8* wfrag = (const bf16x8*)ws;

        f32x4  accN[4];
        bf16x8 w2f[4], w3f[4];
        #pragma unroll
        for (int et = 0; et < 4; ++et) {
            bf16x8 w0, w1;
            if constexpr (USE_WS) {
                w0      = wfrag[(et * 4 + 0) * 64 + lane];
                w1      = wfrag[(et * 4 + 1) * 64 + lane];
                w2f[et] = wfrag[(et * 4 + 2) * 64 + lane];
                w3f[et] = wfrag[(et * 4 + 3) * 64 + lane];
            } else {
                const int col = et * 16 + m16;
                #pragma unroll
                for (int j = 0; j < 8; ++j) {
                    const int k0 = quad * 8 + j;
                    if constexpr (FMODE == 0) {
                        w0[j]      = (short)((const unsigned short*)att_W1)[k0 * D_SZ + col];
                        w1[j]      = (short)((const unsigned short*)att_W1)[(k0 + 32) * D_SZ + col];
                        w2f[et][j] = (short)((const unsigned short*)att_W2)[k0 * D_SZ + col];
                        w3f[et][j] = (short)((const unsigned short*)att_W2)[(k0 + 32) * D_SZ + col];
                    } else {
                        w0[j]      = (short)f2bfbits(((const float*)att_W1)[k0 * D_SZ + col]);
                        w1[j]      = (short)f2bfbits(((const float*)att_W1)[(k0 + 32) * D_SZ + col]);
                        w2f[et][j] = (short)f2bfbits(((const float*)att_W2)[k0 * D_SZ + col]);
                        w3f[et][j] = (short)f2bfbits(((const float*)att_W2)[(k0 + 32) * D_SZ + col]);
                    }
                }
            }
            f32x4 z = {0.f, 0.f, 0.f, 0.f};
            z = __builtin_amdgcn_mfma_f32_16x16x32_bf16(a0, w0, z, 0, 0, 0);
            z = __builtin_amdgcn_mfma_f32_16x16x32_bf16(a1, w1, z, 0, 0, 0);
            accN[et] = z;
        }

        #pragma unroll
        for (int mt = 0; mt < 4; ++mt) {
            const unsigned short* Ar = sm.A + (r * 64 + mt * 16 + m16) * ARS + quad * 8;
            const bf16x8 a2 = *(const bf16x8*)Ar;          // neigh k  0..31
            const bf16x8 a3 = *(const bf16x8*)(Ar + 32);   // neigh k 32..63
            float p0 = 0.f, p1 = 0.f, p2 = 0.f, p3 = 0.f;
            #pragma unroll
            for (int et = 0; et < 4; ++et) {
                f32x4 acc = __builtin_amdgcn_mfma_f32_16x16x32_bf16(a2, w2f[et], accN[et], 0, 0, 0);
                acc       = __builtin_amdgcn_mfma_f32_16x16x32_bf16(a3, w3f[et], acc,      0, 0, 0);
                p0 = fmaf(tanh_fast(acc[0]), vep[et], p0);
                p1 = fmaf(tanh_fast(acc[1]), vep[et], p1);
                p2 = fmaf(tanh_fast(acc[2]), vep[et], p2);
                p3 = fmaf(tanh_fast(acc[3]), vep[et], p3);
            }
            p0 = dpp_add<0xB1>(p0); p0 = dpp_add<0x4E>(p0); p0 = dpp_add<0x124>(p0); p0 = dpp_add<0x128>(p0);
            p1 = dpp_add<0xB1>(p1); p1 = dpp_add<0x4E>(p1); p1 = dpp_add<0x124>(p1); p1 = dpp_add<0x128>(p1);
            p2 = dpp_add<0xB1>(p2); p2 = dpp_add<0x4E>(p2); p2 = dpp_add<0x124>(p2); p2 = dpp_add<0x128>(p2);
            p3 = dpp_add<0xB1>(p3); p3 = dpp_add<0x4E>(p3); p3 = dpp_add<0x124>(p3); p3 = dpp_add<0x128>(p3);
            if (m16 == 0) {
                sm.att[r][mt * 16 + quad * 4 + 0] = p0;
                sm.att[r][mt * 16 + quad * 4 + 1] = p1;
                sm.att[r][mt * 16 + quad * 4 + 2] = p2;
                sm.att[r][mt * 16 + quad * 4 + 3] = p3;
            }
        }
    }

    // ---- Phase 3: scores -> wn IN PLACE over att (per-lane same-slot RAW) ----
    {
        const int r   = wv;
        const float ts = 1.0f / fmaf(2.0f, p3_dt, 1.0f); // Decayer(2,'rev')
        const float lr = ts >= 0.0f ? ts : 0.01f * ts;   // leaky_relu
        const unsigned long long bal = __ballot(p3_m != 0.0f);
        const float cnt = (float)__popcll(bal);
        sm.att[r][lane] = p3_m * lr * sm.att[r][lane] / fmaxf(cnt, 1.0f);

        if constexpr (FMODE == 0) {
            *(unsigned*)(sm.comb + r * CRS + 2 * D_SZ + 2 * lane) = p3_hw;
        } else {
            *(unsigned*)(sm.comb + r * CRS + 2 * D_SZ + 2 * lane) = pack2bf(p3_h0, p3_h1);
        }
    }

    // ---- Phase 4: neigh_agg (wave-private; lane = d; 4 partial accs) ----
    {
        const int r = wv;
        float g0 = 0.f, g1 = 0.f, g2 = 0.f, g3 = 0.f;
        #pragma unroll
        for (int n = 0; n < N_SZ; n += 4) {
            g0 = fmaf(sm.att[r][n + 0], bits2f(sm.A[(r * 64 + n + 0) * ARS + lane]), g0);
            g1 = fmaf(sm.att[r][n + 1], bits2f(sm.A[(r * 64 + n + 1) * ARS + lane]), g1);
            g2 = fmaf(sm.att[r][n + 2], bits2f(sm.A[(r * 64 + n + 2) * ARS + lane]), g2);
            g3 = fmaf(sm.att[r][n + 3], bits2f(sm.A[(r * 64 + n + 3) * ARS + lane]), g3);
        }
        const float agg = (g0 + g1) + (g2 + g3);
        sm.comb[r * CRS + D_SZ + lane] = (unsigned short)f2bfbits(agg);
    }
    __syncthreads();   // ONLY barrier: phase 5 reads both rows' comb

    // ---- Phase 5: GEMV via MFMA. A rows = comb[m16&1] (duplicated), N=128 h, K=256.
    // 2 waves x 4 h-tiles each = 8 tiles of 16 -> 128 outputs.
    {
        bf16x8 AF[8];
        #pragma unroll
        for (int ks = 0; ks < 8; ++ks)
            AF[ks] = *(const bf16x8*)(sm.comb + (m16 & 1) * CRS + ks * 32 + quad * 8);
        #pragma unroll
        for (int t2 = 0; t2 < 4; ++t2) {
            const int nt = wv * 4 + t2;
            f32x4 c = {0.f, 0.f, 0.f, 0.f};
            #pragma unroll
            for (int ks = 0; ks < 8; ++ks) {
                bf16x8 bw;
                if constexpr (FMODE == 0) {
                    bw = *(const bf16x8*)((const unsigned short*)weight
                            + (nt * 16 + m16) * (4 * D_SZ) + ks * 32 + quad * 8);
                } else {
                    const float* wr = (const float*)weight
                            + (nt * 16 + m16) * (4 * D_SZ) + ks * 32 + quad * 8;
                    #pragma unroll
                    for (int j = 0; j < 8; ++j) bw[j] = (short)f2bfbits(wr[j]);
                }
                c = __builtin_amdgcn_mfma_f32_16x16x32_bf16(AF[ks], bw, c, 0, 0, 0);
            }
            if (quad == 0) {   // C rows 0..1 = the 2 distinct comb rows; col = m16
                #pragma unroll
                for (int rr = 0; rr < R_PB; ++rr) {
                    const float v = fmaxf(c[rr], 0.0f);
                    if constexpr (FMODE == 0)
                        ((__hip_bfloat16*)out)[(b0 + rr) * H_SZ + nt * 16 + m16] = __float2bfloat16(v);
                    else
                        ((float*)out)[(b0 + rr) * H_SZ + nt * 16 + m16] = v;
                }
            }
        }
    }
}

template<bool USE_WS>
__global__ __launch_bounds__(64 * R_PB, 4) void fused_model_kernel(
    const void* dt_node, const void* deg_node, const void* cc_node,
    const void* dt_neigh, const void* deg_neigh, const void* cc_neigh,
    const void* neigh_mask, const void* feature_hist,
    const void* t2v_w, const void* t2v_b, const void* node_w, const void* node_b,
    const void* att_W1, const void* att_W2, const void* att_v,
    const void* weight, void* out, const void* ws)
{
    __shared__ Smem sm;
    const int b0  = blockIdx.x * R_PB;
    const int tid = threadIdx.x;

    // wave-uniform dtype detection on head bytes (no LDS, no barrier)
    const int fmode = __builtin_amdgcn_readfirstlane(detect_f32(dt_node));
    const int mmode = __builtin_amdgcn_readfirstlane(detect_mask_mode(neigh_mask));

    if (fmode == 0)
        body<0, USE_WS>(sm, dt_node, deg_node, cc_node, dt_neigh, deg_neigh, cc_neigh,
                        neigh_mask, feature_hist, t2v_w, t2v_b, node_w, node_b,
                        att_W1, att_W2, att_v, weight, out, ws, mmode, b0, tid);
    else
        body<1, USE_WS>(sm, dt_node, deg_node, cc_node, dt_neigh, deg_neigh, cc_neigh,
                        neigh_mask, feature_hist, t2v_w, t2v_b, node_w, node_b,
                        att_W1, att_W2, att_v, weight, out, ws, mmode, b0, tid);
}

extern "C" void kernel_launch(void* const* d_in, const int* in_sizes, int n_in,
                              void* d_out, int out_size, void* d_ws, size_t ws_size,
                              hipStream_t stream) {
    const bool use_ws = (ws_size >= 16384) && (d_ws != nullptr);
    if (use_ws) {
        prep_kernel<<<4, 256, 0, stream>>>(d_in[0], d_in[12], d_in[13], d_ws);
        fused_model_kernel<true><<<B_SZ / R_PB, 64 * R_PB, 0, stream>>>(
            d_in[0], d_in[1], d_in[2], d_in[3], d_in[4], d_in[5], d_in[6], d_in[7],
            d_in[8], d_in[9], d_in[10], d_in[11], d_in[12], d_in[13], d_in[14], d_in[15],
            d_out, d_ws);
    } else {
        fused_model_kernel<false><<<B_SZ / R_PB, 64 * R_PB, 0, stream>>>(
            d_in[0], d_in[1], d_in[2], d_in[3], d_in[4], d_in[5], d_in[6], d_in[7],
            d_in[8], d_in[9], d_in[10], d_in[11], d_in[12], d_in[13], d_in[14], d_in[15],
            d_out, d_ws);
    }
}

// Round 19
// 195.989 us; speedup vs baseline: 1.2642x; 1.2642x over previous
//
#include <hip/hip_runtime.h>
#include <hip/hip_bf16.h>

#define B_SZ 16384
#define N_SZ 64
#define D_SZ 64
#define H_SZ 128
#define R_PB 4              // rows per block (one per wave; phases 1-4 are wave-private)
#define ARS 68              // A row stride, bf16 elems (136 B; 2-way banks = free)
#define CRS 264             // comb row stride, bf16 elems (payload 256; 528 B keeps 16B align)

#define INV_2PI 0.15915494309189535f
#define TWO_PI  6.283185307179586f

typedef short bf16x8 __attribute__((ext_vector_type(8)));
typedef float f32x4  __attribute__((ext_vector_type(4)));
typedef float f32x2  __attribute__((ext_vector_type(2)));

__device__ __forceinline__ float bits2f(unsigned short r){union{unsigned i;float f;}c;c.i=((unsigned)r)<<16;return c.f;}
__device__ __forceinline__ unsigned f2bfbits(float f){
    __hip_bfloat16 h = __float2bfloat16(f);           // RNE
    unsigned short u;
    __builtin_memcpy(&u, &h, 2);
    return (unsigned)u;
}
__device__ __forceinline__ unsigned pack2bf(float a, float b){   // v_cvt_pk_bf16_f32
    __hip_bfloat162 h = __float22bfloat162_rn(make_float2(a, b));
    unsigned r;
    __builtin_memcpy(&r, &h, 4);
    return r;
}
__device__ __forceinline__ float bf2f(__hip_bfloat16 x) { return __bfloat162float(x); }

template<int CTRL>
__device__ __forceinline__ float dpp_add(float v){
    int t = __builtin_amdgcn_mov_dpp(__builtin_bit_cast(int, v), CTRL, 0xf, 0xf, true);
    return v + __builtin_bit_cast(float, t);
}

// cos of a value ALREADY in revolutions: v_fract (ISA range reduction) + v_cos.
__device__ __forceinline__ float cos_rev(float v_rev){
    return __builtin_amdgcn_cosf(__builtin_amdgcn_fractf(v_rev));
}

// 1/max(sqrt(ss),1e-12) as a single v_rsq + clamp (ss >= 0 by construction).
__device__ __forceinline__ float inv_norm(float ss){
    return fminf(__builtin_amdgcn_rsqf(ss), 1e12f);
}

// Packed clamped Pade 3/2 tanh on 2 values: pk_mul/pk_fma halve the VALU count
// vs scalar; 2x v_rcp (trans) unchanged; clamp stays per-element v_med3.
__device__ __forceinline__ f32x2 tanh2(f32x2 x){
    const f32x2 t   = x * x;                           // v_pk_mul_f32
    const f32x2 num = x * (t + 27.0f);                 // pk_add + pk_mul
    const f32x2 den = t * 9.0f + 27.0f;                // v_pk_fma_f32
    f32x2 rc;
    rc.x = __builtin_amdgcn_rcpf(den.x);               // v_rcp_f32
    rc.y = __builtin_amdgcn_rcpf(den.y);
    f32x2 r = num * rc;                                // v_pk_mul_f32
    r.x = fminf(1.0f, fmaxf(-1.0f, r.x));              // v_med3
    r.y = fminf(1.0f, fmaxf(-1.0f, r.y));
    return r;
}

// FMODE 0: bf16 tensors, 1: f32 tensors
template<int FMODE>
__device__ __forceinline__ float LD(const void* p, int i) {
    if constexpr (FMODE == 0) return bf2f(((const __hip_bfloat16*)p)[i]);
    else                      return ((const float*)p)[i];
}

// mask modes: 0 = int32, 1 = int8/bool, 2 = bf16, 3 = f32
__device__ __forceinline__ float mval(const void* p, int i, int mode) {
    if (mode == 0) return ((const int*)p)[i]            ? 1.0f : 0.0f;
    if (mode == 1) return ((const unsigned char*)p)[i]  ? 1.0f : 0.0f;
    if (mode == 2) return ((const unsigned short*)p)[i] ? 1.0f : 0.0f;
    return ((const unsigned int*)p)[i]                  ? 1.0f : 0.0f;
}

// dt_node strictly positive: bf16 words never set bit15; f32 low-mantissa words do
__device__ __forceinline__ int detect_f32(const void* p) {
    const uint4* q = (const uint4*)p;
    unsigned o = 0;
    #pragma unroll
    for (int i = 0; i < 8; ++i) { uint4 v = q[i]; o |= v.x | v.y | v.z | v.w; }
    return (o & 0x80008000u) ? 1 : 0;
}

// 0/1-valued mask, 128 head bytes
__device__ __forceinline__ int detect_mask_mode(const void* p) {
    const uint4* q = (const uint4*)p;
    unsigned oa = 0, ofe = 0;
    #pragma unroll
    for (int i = 0; i < 8; ++i) {
        uint4 v = q[i];
        unsigned w = v.x | v.y | v.z | v.w;
        oa  |= w;
        ofe |= (v.x & 0xFEFEFEFEu) | (v.y & 0xFEFEFEFEu) | (v.z & 0xFEFEFEFEu) | (v.w & 0xFEFEFEFEu);
    }
    if ((oa & 0xFFFFFF00u) == 0) return 0;   // int32 0/1
    if (ofe == 0)                return 1;   // bool/int8
    if (oa & 0x000000FEu)        return 2;   // bf16
    return 3;                                // f32
}

// ---------------- prep: W1/W2 -> MFMA B-fragment layout in d_ws (16 KB), grid=4 ----------------
__global__ void prep_kernel(const void* dt_node, const void* att_W1, const void* att_W2,
                            void* ws) {
    const int t     = blockIdx.x * 256 + threadIdx.x;
    const int fmode = detect_f32(dt_node);
    const int fi  = t >> 6, ln = t & 63;
    const int et  = fi >> 2, ks = fi & 3;
    const int m16 = ln & 15, qd = ln >> 4;
    const int col = et * 16 + m16;
    unsigned short s[8];
    #pragma unroll
    for (int j = 0; j < 8; ++j) {
        const int i = ks * 32 + qd * 8 + j;
        if (fmode == 0) {
            s[j] = (i < 64) ? ((const unsigned short*)att_W1)[i * D_SZ + col]
                            : ((const unsigned short*)att_W2)[(i - 64) * D_SZ + col];
        } else {
            const float v = (i < 64) ? ((const float*)att_W1)[i * D_SZ + col]
                                     : ((const float*)att_W2)[(i - 64) * D_SZ + col];
            s[j] = (unsigned short)f2bfbits(v);
        }
    }
    ((uint4*)ws)[t] = make_uint4(((unsigned)s[0]) | (((unsigned)s[1]) << 16),
                                 ((unsigned)s[2]) | (((unsigned)s[3]) << 16),
                                 ((unsigned)s[4]) | (((unsigned)s[5]) << 16),
                                 ((unsigned)s[6]) | (((unsigned)s[7]) << 16));
}

struct Smem {
    alignas(16) unsigned short A[R_PB * 64 * ARS];  // [row][n 0..63][d] neighbors only (node lives in comb)
    alignas(16) unsigned short comb[R_PB * CRS];    // [node_f(64) | agg(64) | hist(128)] bf16 + pad
    alignas(16) float prm[4][D_SZ];                 // t2v_w/2pi | t2v_b/2pi | node_w | 2*node_b
    float att[R_PB][N_SZ];                          // phase2: att scores; phase3 overwrites wn
};
// LDS total = 34816 + 2112 + 1024 + 1024 = 38976 B (alloc 39424).

// ---- 4-row interleaved feature chunk; rows are CONSECUTIVE (fb*4+r) so the
// phase-1 inputs come from one ushort4/float4 load. ss accumulated packed.
__device__ __forceinline__ void feat_row4(const float t[4], const float dc[4],
                                          const float* sw, const float* sb,
                                          const float* snw, const float* snb,
                                          int c, unsigned short* dstA, int rstride) {
    f32x2 fp[4][8];
    f32x2 ssv[4] = {{0.f,0.f},{0.f,0.f},{0.f,0.f},{0.f,0.f}};
    #pragma unroll
    for (int g = 0; g < 8; ++g) {
        const f32x2 w  = *(const f32x2*)(sw  + 2 * g);
        const f32x2 b  = *(const f32x2*)(sb  + 2 * g);
        const f32x2 nw = *(const f32x2*)(snw + 2 * g);
        const f32x2 nb = *(const f32x2*)(snb + 2 * g);
        #pragma unroll
        for (int r = 0; r < 4; ++r) {
            f32x2 v = w * t[r] + b;                     // v_pk_fma_f32 (REVOLUTIONS)
            f32x2 cv;
            cv.x = (c == 0 && g == 0) ? v.x * TWO_PI : cos_rev(v.x);
            cv.y = cos_rev(v.y);
            f32x2 f = cv + (nw * dc[r] + nb);
            ssv[r] = f * f + ssv[r];                    // v_pk_fma_f32
            fp[r][g] = f;
        }
    }
    #pragma unroll
    for (int r = 0; r < 4; ++r) {
        float s = ssv[r].x + ssv[r].y;
        s = dpp_add<0xB1>(s);                           // quad_perm xor1
        s = dpp_add<0x4E>(s);                           // quad_perm xor2
        const float inv = inv_norm(s);
        unsigned pk[8];
        #pragma unroll
        for (int g = 0; g < 8; ++g)
            pk[g] = pack2bf(fp[r][g].x * inv, fp[r][g].y * inv);
        uint4* d = (uint4*)(dstA + r * rstride);
        d[0] = make_uint4(pk[0], pk[1], pk[2], pk[3]);
        d[1] = make_uint4(pk[4], pk[5], pk[6], pk[7]);
    }
}

// single-row variant (node tail, lanes 0-3)
__device__ __forceinline__ void feat_row(float t, float dc,
                                         const float* sw, const float* sb,
                                         const float* snw, const float* snb,
                                         int c, unsigned short* dstC) {
    f32x2 fp[8]; f32x2 ssv = {0.f, 0.f};
    #pragma unroll
    for (int g = 0; g < 8; ++g) {
        const f32x2 w  = *(const f32x2*)(sw  + 2 * g);
        const f32x2 b  = *(const f32x2*)(sb  + 2 * g);
        const f32x2 nw = *(const f32x2*)(snw + 2 * g);
        const f32x2 nb = *(const f32x2*)(snb + 2 * g);
        f32x2 v = w * t + b;
        f32x2 cv;
        cv.x = (c == 0 && g == 0) ? v.x * TWO_PI : cos_rev(v.x);
        cv.y = cos_rev(v.y);
        f32x2 f = cv + (nw * dc + nb);
        ssv = f * f + ssv;
        fp[g] = f;
    }
    float ss = ssv.x + ssv.y;
    ss = dpp_add<0xB1>(ss);
    ss = dpp_add<0x4E>(ss);
    const float inv = inv_norm(ss);
    unsigned pk[8];
    #pragma unroll
    for (int g = 0; g < 8; ++g)
        pk[g] = pack2bf(fp[g].x * inv, fp[g].y * inv);
    ((uint4*)dstC)[0] = make_uint4(pk[0], pk[1], pk[2], pk[3]);
    ((uint4*)dstC)[1] = make_uint4(pk[4], pk[5], pk[6], pk[7]);
}

template<int FMODE, bool USE_WS>
__device__ __forceinline__ void body(
    Smem& sm,
    const void* dt_node, const void* deg_node, const void* cc_node,
    const void* dt_neigh, const void* deg_neigh, const void* cc_neigh,
    const void* neigh_mask, const void* feature_hist,
    const void* t2v_w, const void* t2v_b, const void* node_w, const void* node_b,
    const void* att_W1, const void* att_W2, const void* att_v,
    const void* weight, void* out, const void* ws, int mmode, int b0, int tid)
{
    const int lane = tid & 63;
    const int wv   = tid >> 6;
    const int m16  = lane & 15;
    const int quad = lane >> 4;
    const int row  = b0 + wv;       // this wave's row; phases 1-4 are wave-private

    // ---- Prefetch (a): phase-1 inputs, VECTORIZED. Thread handles 4 CONSECUTIVE
    // neighbors fb*4..fb*4+3 -> one ushort4/float4 load per array (was 12 scalar).
    const int fb = lane >> 2;       // 4-neighbor group; c = lane&3 = chunk
    float p1_dt[4], p1_deg[4], p1_cc[4];
    {
        const int v4 = row * 16 + fb;
        if constexpr (FMODE == 0) {
            const ushort4 a = ((const ushort4*)dt_neigh)[v4];
            const ushort4 d = ((const ushort4*)deg_neigh)[v4];
            const ushort4 e = ((const ushort4*)cc_neigh)[v4];
            p1_dt[0]=bits2f(a.x); p1_dt[1]=bits2f(a.y); p1_dt[2]=bits2f(a.z); p1_dt[3]=bits2f(a.w);
            p1_deg[0]=bits2f(d.x); p1_deg[1]=bits2f(d.y); p1_deg[2]=bits2f(d.z); p1_deg[3]=bits2f(d.w);
            p1_cc[0]=bits2f(e.x); p1_cc[1]=bits2f(e.y); p1_cc[2]=bits2f(e.z); p1_cc[3]=bits2f(e.w);
        } else {
            const float4 a = ((const float4*)dt_neigh)[v4];
            const float4 d = ((const float4*)deg_neigh)[v4];
            const float4 e = ((const float4*)cc_neigh)[v4];
            p1_dt[0]=a.x; p1_dt[1]=a.y; p1_dt[2]=a.z; p1_dt[3]=a.w;
            p1_deg[0]=d.x; p1_deg[1]=d.y; p1_deg[2]=d.z; p1_deg[3]=d.w;
            p1_cc[0]=e.x; p1_cc[1]=e.y; p1_cc[2]=e.z; p1_cc[3]=e.w;
        }
    }
    const float pn_dt  = LD<FMODE>(dt_node,  row);
    const float pn_deg = LD<FMODE>(deg_node, row);
    const float pn_cc  = LD<FMODE>(cc_node,  row);

    // ---- Prefetch (b): phase-3 inputs for this row ----
    const int p3idx = row * N_SZ + lane;
    const float p3_dt = LD<FMODE>(dt_neigh, p3idx);
    const float p3_m  = mval(neigh_mask, p3idx, mmode);
    unsigned p3_hw = 0; float p3_h0 = 0.f, p3_h1 = 0.f;
    if constexpr (FMODE == 0) {
        p3_hw = ((const unsigned*)feature_hist)[row * 64 + lane];
    } else {
        const float* fh = (const float*)feature_hist + row * 2 * D_SZ + 2 * lane;
        p3_h0 = fh[0]; p3_h1 = fh[1];
    }
    float vep[4];
    #pragma unroll
    for (int et = 0; et < 4; ++et) vep[et] = LD<FMODE>(att_v, et * 16 + m16);

    // ---- Phase 0': EACH wave stages the FULL param block (benign identical-bits
    // race; a wave's own writes cover every entry it reads -> NO barrier).
    #pragma unroll
    for (int arr = 0; arr < 4; ++arr) {
        float v;
        if      (arr == 0) v = INV_2PI * LD<FMODE>(t2v_w,  lane);
        else if (arr == 1) v = INV_2PI * LD<FMODE>(t2v_b,  lane);
        else if (arr == 2) v = LD<FMODE>(node_w, lane);
        else               v = 2.0f * LD<FMODE>(node_b, lane);   // deg+cc biases folded
        sm.prm[arr][lane] = v;
    }

    // ---- Phase 1': wave-private features, 4 consecutive rows batched. No barrier
    // after: phases 2-4 read only this wave's LDS slices (same-wave RAW ordered).
    {
        const int c = lane & 3, d0 = c * 16;
        const float* sw  = sm.prm[0] + d0;
        const float* sb  = sm.prm[1] + d0;
        const float* snw = sm.prm[2] + d0;
        const float* snb = sm.prm[3] + d0;

        float tt[4], dcc[4];
        #pragma unroll
        for (int it = 0; it < 4; ++it) {
            tt[it]  = fabsf(p1_dt[it]);
            dcc[it] = p1_deg[it] + p1_cc[it];
        }
        feat_row4(tt, dcc, sw, sb, snw, snb, c,
                  sm.A + (wv * 64 + fb * 4) * ARS + d0, ARS);

        if (fb == 0)   // lanes 0-3: node feature row -> comb only
            feat_row(fabsf(pn_dt), pn_deg + pn_cc, sw, sb, snw, snb, c,
                     sm.comb + wv * CRS + d0);
    }

    // ---- Phase 2: S + att for row r = wv ----
    // S[m][e] = node@W1[e] (once per e-tile) + neigh[m]@W2[e]; node frags from comb.
    {
        const int r = wv;
        const unsigned short* An = sm.comb + r * CRS + quad * 8;
        const bf16x8 a0 = *(const bf16x8*)An;          // node k  0..31
        const bf16x8 a1 = *(const bf16x8*)(An + 32);   // node k 32..63
        const bf16x8* wfrag = (const bf16x8*)ws;

        f32x4  accN[4];
        bf16x8 w2f[4], w3f[4];
        #pragma unroll
        for (int et = 0; et < 4; ++et) {
            bf16x8 w0, w1;
            if constexpr (USE_WS) {
                w0      = wfrag[(et * 4 + 0) * 64 + lane];
                w1      = wfrag[(et * 4 + 1) * 64 + lane];
                w2f[et] = wfrag[(et * 4 + 2) * 64 + lane];
                w3f[et] = wfrag[(et * 4 + 3) * 64 + lane];
            } else {
                const int col = et * 16 + m16;
                #pragma unroll
                for (int j = 0; j < 8; ++j) {
                    const int k0 = quad * 8 + j;
                    if constexpr (FMODE == 0) {
                        w0[j]      = (short)((const unsigned short*)att_W1)[k0 * D_SZ + col];
                        w1[j]      = (short)((const unsigned short*)att_W1)[(k0 + 32) * D_SZ + col];
                        w2f[et][j] = (short)((const unsigned short*)att_W2)[k0 * D_SZ + col];
                        w3f[et][j] = (short)((const unsigned short*)att_W2)[(k0 + 32) * D_SZ + col];
                    } else {
                        w0[j]      = (short)f2bfbits(((const float*)att_W1)[k0 * D_SZ + col]);
                        w1[j]      = (short)f2bfbits(((const float*)att_W1)[(k0 + 32) * D_SZ + col]);
                        w2f[et][j] = (short)f2bfbits(((const float*)att_W2)[k0 * D_SZ + col]);
                        w3f[et][j] = (short)f2bfbits(((const float*)att_W2)[(k0 + 32) * D_SZ + col]);
                    }
                }
            }
            f32x4 z = {0.f, 0.f, 0.f, 0.f};
            z = __builtin_amdgcn_mfma_f32_16x16x32_bf16(a0, w0, z, 0, 0, 0);
            z = __builtin_amdgcn_mfma_f32_16x16x32_bf16(a1, w1, z, 0, 0, 0);
            accN[et] = z;
        }

        #pragma unroll
        for (int mt = 0; mt < 4; ++mt) {
            const unsigned short* Ar = sm.A + (r * 64 + mt * 16 + m16) * ARS + quad * 8;
            const bf16x8 a2 = *(const bf16x8*)Ar;          // neigh k  0..31
            const bf16x8 a3 = *(const bf16x8*)(Ar + 32);   // neigh k 32..63
            f32x2 p01 = {0.f, 0.f}, p23 = {0.f, 0.f};
            #pragma unroll
            for (int et = 0; et < 4; ++et) {
                f32x4 acc = __builtin_amdgcn_mfma_f32_16x16x32_bf16(a2, w2f[et], accN[et], 0, 0, 0);
                acc       = __builtin_amdgcn_mfma_f32_16x16x32_bf16(a3, w3f[et], acc,      0, 0, 0);
                f32x2 x01 = {acc[0], acc[1]};
                f32x2 x23 = {acc[2], acc[3]};
                const float ve = vep[et];
                p01 = tanh2(x01) * ve + p01;               // v_pk_fma_f32
                p23 = tanh2(x23) * ve + p23;
            }
            float p0 = p01.x, p1 = p01.y, p2 = p23.x, p3 = p23.y;
            p0 = dpp_add<0xB1>(p0); p0 = dpp_add<0x4E>(p0); p0 = dpp_add<0x124>(p0); p0 = dpp_add<0x128>(p0);
            p1 = dpp_add<0xB1>(p1); p1 = dpp_add<0x4E>(p1); p1 = dpp_add<0x124>(p1); p1 = dpp_add<0x128>(p1);
            p2 = dpp_add<0xB1>(p2); p2 = dpp_add<0x4E>(p2); p2 = dpp_add<0x124>(p2); p2 = dpp_add<0x128>(p2);
            p3 = dpp_add<0xB1>(p3); p3 = dpp_add<0x4E>(p3); p3 = dpp_add<0x124>(p3); p3 = dpp_add<0x128>(p3);
            if (m16 == 0) {
                sm.att[r][mt * 16 + quad * 4 + 0] = p0;
                sm.att[r][mt * 16 + quad * 4 + 1] = p1;
                sm.att[r][mt * 16 + quad * 4 + 2] = p2;
                sm.att[r][mt * 16 + quad * 4 + 3] = p3;
            }
        }
    }

    // ---- Phase 3: scores -> wn IN PLACE over att (per-lane same-slot RAW) ----
    {
        const int r   = wv;
        const float ts = 1.0f / fmaf(2.0f, p3_dt, 1.0f); // Decayer(2,'rev')
        const float lr = ts >= 0.0f ? ts : 0.01f * ts;   // leaky_relu
        const unsigned long long bal = __ballot(p3_m != 0.0f);
        const float cnt = (float)__popcll(bal);
        sm.att[r][lane] = p3_m * lr * sm.att[r][lane] / fmaxf(cnt, 1.0f);

        if constexpr (FMODE == 0) {
            *(unsigned*)(sm.comb + r * CRS + 2 * D_SZ + 2 * lane) = p3_hw;
        } else {
            *(unsigned*)(sm.comb + r * CRS + 2 * D_SZ + 2 * lane) = pack2bf(p3_h0, p3_h1);
        }
    }

    // ---- Phase 4: neigh_agg (wave-private; lane = d; 4 partial accs) ----
    {
        const int r = wv;
        float g0 = 0.f, g1 = 0.f, g2 = 0.f, g3 = 0.f;
        #pragma unroll
        for (int n = 0; n < N_SZ; n += 4) {
            g0 = fmaf(sm.att[r][n + 0], bits2f(sm.A[(r * 64 + n + 0) * ARS + lane]), g0);
            g1 = fmaf(sm.att[r][n + 1], bits2f(sm.A[(r * 64 + n + 1) * ARS + lane]), g1);
            g2 = fmaf(sm.att[r][n + 2], bits2f(sm.A[(r * 64 + n + 2) * ARS + lane]), g2);
            g3 = fmaf(sm.att[r][n + 3], bits2f(sm.A[(r * 64 + n + 3) * ARS + lane]), g3);
        }
        const float agg = (g0 + g1) + (g2 + g3);
        sm.comb[r * CRS + D_SZ + lane] = (unsigned short)f2bfbits(agg);
    }
    __syncthreads();   // ONLY barrier: phase 5 reads all 4 rows' comb

    // ---- Phase 5: GEMV via MFMA. A rows = comb[m16&3] (duplicated), N=128 h, K=256 ----
    {
        bf16x8 AF[8];
        #pragma unroll
        for (int ks = 0; ks < 8; ++ks)
            AF[ks] = *(const bf16x8*)(sm.comb + (m16 & 3) * CRS + ks * 32 + quad * 8);
        #pragma unroll
        for (int t2 = 0; t2 < 2; ++t2) {
            const int nt = wv * 2 + t2;
            f32x4 c = {0.f, 0.f, 0.f, 0.f};
            #pragma unroll
            for (int ks = 0; ks < 8; ++ks) {
                bf16x8 bw;
                if constexpr (FMODE == 0) {
                    bw = *(const bf16x8*)((const unsigned short*)weight
                            + (nt * 16 + m16) * (4 * D_SZ) + ks * 32 + quad * 8);
                } else {
                    const float* wr = (const float*)weight
                            + (nt * 16 + m16) * (4 * D_SZ) + ks * 32 + quad * 8;
                    #pragma unroll
                    for (int j = 0; j < 8; ++j) bw[j] = (short)f2bfbits(wr[j]);
                }
                c = __builtin_amdgcn_mfma_f32_16x16x32_bf16(AF[ks], bw, c, 0, 0, 0);
            }
            if (quad == 0) {   // C rows 0..3 = quad 0, regs 0..3; col = m16
                #pragma unroll
                for (int rr = 0; rr < R_PB; ++rr) {
                    const float v = fmaxf(c[rr], 0.0f);
                    if constexpr (FMODE == 0)
                        ((__hip_bfloat16*)out)[(b0 + rr) * H_SZ + nt * 16 + m16] = __float2bfloat16(v);
                    else
                        ((float*)out)[(b0 + rr) * H_SZ + nt * 16 + m16] = v;
                }
            }
        }
    }
}

template<bool USE_WS>
__global__ __launch_bounds__(256, 4) void fused_model_kernel(
    const void* dt_node, const void* deg_node, const void* cc_node,
    const void* dt_neigh, const void* deg_neigh, const void* cc_neigh,
    const void* neigh_mask, const void* feature_hist,
    const void* t2v_w, const void* t2v_b, const void* node_w, const void* node_b,
    const void* att_W1, const void* att_W2, const void* att_v,
    const void* weight, void* out, const void* ws)
{
    __shared__ Smem sm;
    const int b0  = blockIdx.x * R_PB;
    const int tid = threadIdx.x;

    // wave-uniform dtype detection on head bytes (no LDS, no barrier)
    const int fmode = __builtin_amdgcn_readfirstlane(detect_f32(dt_node));
    const int mmode = __builtin_amdgcn_readfirstlane(detect_mask_mode(neigh_mask));

    if (fmode == 0)
        body<0, USE_WS>(sm, dt_node, deg_node, cc_node, dt_neigh, deg_neigh, cc_neigh,
                        neigh_mask, feature_hist, t2v_w, t2v_b, node_w, node_b,
                        att_W1, att_W2, att_v, weight, out, ws, mmode, b0, tid);
    else
        body<1, USE_WS>(sm, dt_node, deg_node, cc_node, dt_neigh, deg_neigh, cc_neigh,
                        neigh_mask, feature_hist, t2v_w, t2v_b, node_w, node_b,
                        att_W1, att_W2, att_v, weight, out, ws, mmode, b0, tid);
}

extern "C" void kernel_launch(void* const* d_in, const int* in_sizes, int n_in,
                              void* d_out, int out_size, void* d_ws, size_t ws_size,
                              hipStream_t stream) {
    const bool use_ws = (ws_size >= 16384) && (d_ws != nullptr);
    if (use_ws) {
        prep_kernel<<<4, 256, 0, stream>>>(d_in[0], d_in[12], d_in[13], d_ws);
        fused_model_kernel<true><<<B_SZ / R_PB, 256, 0, stream>>>(
            d_in[0], d_in[1], d_in[2], d_in[3], d_in[4], d_in[5], d_in[6], d_in[7],
            d_in[8], d_in[9], d_in[10], d_in[11], d_in[12], d_in[13], d_in[14], d_in[15],
            d_out, d_ws);
    } else {
        fused_model_kernel<false><<<B_SZ / R_PB, 256, 0, stream>>>(
            d_in[0], d_in[1], d_in[2], d_in[3], d_in[4], d_in[5], d_in[6], d_in[7],
            d_in[8], d_in[9], d_in[10], d_in[11], d_in[12], d_in[13], d_in[14], d_in[15],
            d_out, d_ws);
    }
}